// Round 5
// baseline (577.798 us; speedup 1.0000x reference)
//
#include <hip/hip_runtime.h>

// MiniSelfAttention: B=8, T=2048, D=1024, fp32 in/out, fp16 MFMA internally.
// R5: wave-tile enlargement — 128x128 block tile, TWO waves of 64x128 each
// (4 M-frags x 8 N-frags, 32 MFMA / 12 ds_read_b128 per wave per K-32).
// Cuts LDS read traffic 32->24 KB per block-iter (A rows wave-private) and
// amortizes the ds_read->MFMA chain 2x. Dbuf + raw-barrier loop kept from R4.
//
// ws layout (MB):
//   [0,6)    WqkvT = WqT|WkT|WvT contiguous (fp16 [3072][1024])
//   [6,8)    WpT fp16
//   [8,40)   q fp16 [8][2048][1024]   (later overwritten by ctx)
//   [40,72)  k fp16
//   [72,104) vT fp16 [8][1024][2048]
//   [104,136) x16 fp16 (dead after QKV), overlaid by:
//   [104,168) S fp16 [8][2048][2048]  (softmaxed in place -> P)

typedef _Float16 half_t;
typedef _Float16 half8 __attribute__((ext_vector_type(8)));
typedef float floatx4 __attribute__((ext_vector_type(4)));

// async global->LDS, 16B per lane; LDS dest = wave-uniform base + lane*16
#define GLD16(gp, lp)                                                          \
    __builtin_amdgcn_global_load_lds(                                          \
        (const __attribute__((address_space(1))) void*)(gp),                   \
        (__attribute__((address_space(3))) void*)(lp), 16, 0, 0)

#define WAIT_VM0()  asm volatile("s_waitcnt vmcnt(0)" ::: "memory")
#define BARRIER()   do { asm volatile("" ::: "memory");                        \
                         __builtin_amdgcn_s_barrier();                         \
                         asm volatile("" ::: "memory"); } while (0)

// ---------------------------------------------------------------------------
// fp16 NT GEMM: 128x128 tile, BK=32, 2 waves (64x128 each), 16x16x32 frags,
// double-buffered LDS + raw-barrier pipeline (1 barrier/iter)
// EPI: 0 = fp16 C store; 1 = fp32 C + bias; 2 = QKV-routed (q*1/32, k, vT)
// ---------------------------------------------------------------------------
template<int EPI>
__global__ __launch_bounds__(128, 2)
void gemm16(const half_t* __restrict__ A, const half_t* __restrict__ B,
            void* __restrict__ Cv, void* __restrict__ C2, void* __restrict__ C3,
            const float* __restrict__ bias, int K, int lda, int ldb, int ldc,
            long long bsA, long long bsB, long long bsC)
{
    __shared__ half_t As[2 * 128 * 32];  // unpadded (global_load_lds), 2 buffers
    __shared__ half_t Bs[2 * 128 * 32];

    const int tid  = threadIdx.x;
    const int lane = tid & 63;
    const int wid  = tid >> 6;          // 0 or 1
    const int wr   = wid * 64;          // wave row offset; waves span all 128 cols
    const long long z = blockIdx.z;
    const int rowBase = blockIdx.y * 128;
    const int colBase = blockIdx.x * 128;

    // staging: wave w stages A rows [w*64, w*64+64) and B rows (cols) likewise,
    // four 1KB global_load_lds each (16 rows x 64B per instruction)
    const int srow = wid * 64 + (lane >> 2);
    const int scol = (lane & 3) * 8;

    const half_t* gA = A + z * bsA + (long long)(rowBase + srow) * lda + scol;
    const half_t* gB = B + z * bsB + (long long)(colBase + srow) * ldb + scol;
    const int lso = (wid * 64) * 32;    // wave-uniform LDS offset (halves)

    floatx4 acc[4][8];
    #pragma unroll
    for (int m = 0; m < 4; ++m)
        #pragma unroll
        for (int n = 0; n < 8; ++n)
            #pragma unroll
            for (int j = 0; j < 4; ++j) acc[m][n][j] = 0.0f;

    const int fr = lane & 15;
    const int fk = (lane >> 4) * 8;
    const int nIter = K >> 5;

    // prolog: stage tile 0 into buffer 0
    #pragma unroll
    for (int j = 0; j < 4; ++j) {
        GLD16(gA + (long long)(16 * j) * lda, &As[lso + (16 * j) * 32]);
        GLD16(gB + (long long)(16 * j) * ldb, &Bs[lso + (16 * j) * 32]);
    }
    WAIT_VM0();
    BARRIER();

    for (int it = 0; it < nIter; ++it) {
        const int cur = (it & 1) * 4096;
        const int nxt = 4096 - cur;
        // prefetch tile it+1 into the other buffer (DMA flies during MFMA)
        if (it + 1 < nIter) {
            const int kk = (it + 1) << 5;
            #pragma unroll
            for (int j = 0; j < 4; ++j) {
                GLD16(gA + (long long)(16 * j) * lda + kk, &As[nxt + lso + (16 * j) * 32]);
                GLD16(gB + (long long)(16 * j) * ldb + kk, &Bs[nxt + lso + (16 * j) * 32]);
            }
        }

        half8 af[4], bf[8];
        #pragma unroll
        for (int m = 0; m < 4; ++m)
            af[m] = *(const half8*)&As[cur + (wr + m * 16 + fr) * 32 + fk];
        #pragma unroll
        for (int n = 0; n < 8; ++n)
            bf[n] = *(const half8*)&Bs[cur + (n * 16 + fr) * 32 + fk];
        #pragma unroll
        for (int m = 0; m < 4; ++m)
            #pragma unroll
            for (int n = 0; n < 8; ++n)
                acc[m][n] = __builtin_amdgcn_mfma_f32_16x16x32_f16(af[m], bf[n], acc[m][n], 0, 0, 0);

        // drain own prefetch DMAs (hidden behind the MFMA above), then publish
        WAIT_VM0();
        BARRIER();
    }

    // epilogue: C/D layout col=lane&15, row=(lane>>4)*4+reg (gfx950-verified)
    const int ecol = lane & 15;
    const int q4   = (lane >> 4) * 4;
    #pragma unroll
    for (int m = 0; m < 4; ++m) {
        #pragma unroll
        for (int n = 0; n < 8; ++n) {
            const int gcol = colBase + n * 16 + ecol;
            #pragma unroll
            for (int r = 0; r < 4; ++r) {
                const int grow = rowBase + wr + m * 16 + q4 + r;
                float v = acc[m][n][r];
                if (EPI == 0) {
                    ((half_t*)Cv)[z * bsC + (long long)grow * ldc + gcol] = (half_t)v;
                } else if (EPI == 1) {
                    ((float*)Cv)[(long long)grow * ldc + gcol] = v + bias[gcol];
                } else {
                    // QKV routing: block-uniform on colBase (128-col block
                    // lies entirely inside one of q/k/v's 1024-col spans)
                    const int mat = colBase >> 10;      // 0=q, 1=k, 2=v
                    const int c   = gcol & 1023;
                    if (mat == 0) {
                        ((half_t*)Cv)[(long long)grow * 1024 + c] = (half_t)(v * 0.03125f);
                    } else if (mat == 1) {
                        ((half_t*)C2)[(long long)grow * 1024 + c] = (half_t)v;
                    } else {
                        // vT[b][c][t], b=grow>>11, t=grow&2047
                        const long long bb = grow >> 11;
                        const long long tt = grow & 2047;
                        ((half_t*)C3)[bb * (1024LL * 2048) + (long long)c * 2048 + tt] = (half_t)v;
                    }
                }
            }
        }
    }
}

// fp32 -> fp16 flat cast, 8 elems/thread
__global__ __launch_bounds__(256)
void cast16(const float* __restrict__ x, half_t* __restrict__ y)
{
    const long long i = ((long long)blockIdx.x * 256 + threadIdx.x) * 8;
    floatx4 a = *(const floatx4*)(x + i);
    floatx4 b = *(const floatx4*)(x + i + 4);
    half8 h;
    #pragma unroll
    for (int j = 0; j < 4; ++j) { h[j] = (half_t)a[j]; h[j + 4] = (half_t)b[j]; }
    *(half8*)(y + i) = h;
}

// 1024x1024 fp32 -> fp16 transposed; grid.z selects which weight
__global__ __launch_bounds__(256)
void cast_transpose4(const float* __restrict__ W0, const float* __restrict__ W1,
                     const float* __restrict__ W2, const float* __restrict__ W3,
                     half_t* __restrict__ WT)
{
    const float* W = (blockIdx.z == 0) ? W0 : (blockIdx.z == 1) ? W1
                   : (blockIdx.z == 2) ? W2 : W3;
    half_t* O = WT + (long long)blockIdx.z * 1024 * 1024;
    __shared__ float t[32][33];
    const int bx = blockIdx.x * 32, by = blockIdx.y * 32;
    const int tx = threadIdx.x, ty = threadIdx.y;
    #pragma unroll
    for (int i = 0; i < 32; i += 8)
        t[ty + i][tx] = W[(long long)(by + ty + i) * 1024 + bx + tx];
    __syncthreads();
    #pragma unroll
    for (int i = 0; i < 32; i += 8)
        O[(long long)(bx + ty + i) * 1024 + by + tx] = (half_t)t[tx][ty + i];
}

// in-place fp16 row softmax over 2048; one 256-thr block per row; half8 I/O
__global__ __launch_bounds__(256)
void softmax_rows(half_t* __restrict__ S)
{
    const long long base = (long long)blockIdx.x * 2048;
    const int t = threadIdx.x;
    half8 h = *(const half8*)(S + base + t * 8);
    float v[8];
    #pragma unroll
    for (int i = 0; i < 8; ++i) v[i] = (float)h[i];
    float m = -3.0e38f;
    #pragma unroll
    for (int i = 0; i < 8; ++i) m = fmaxf(m, v[i]);
    #pragma unroll
    for (int off = 32; off > 0; off >>= 1) m = fmaxf(m, __shfl_down(m, off));
    __shared__ float redm[4], reds[4];
    const int lane = t & 63, wid = t >> 6;
    if (lane == 0) redm[wid] = m;
    __syncthreads();
    const float M = fmaxf(fmaxf(redm[0], redm[1]), fmaxf(redm[2], redm[3]));
    float s = 0.f;
    #pragma unroll
    for (int i = 0; i < 8; ++i) { v[i] = __expf(v[i] - M); s += v[i]; }
    #pragma unroll
    for (int off = 32; off > 0; off >>= 1) s += __shfl_down(s, off);
    if (lane == 0) reds[wid] = s;
    __syncthreads();
    const float inv = 1.0f / (reds[0] + reds[1] + reds[2] + reds[3]);
    #pragma unroll
    for (int i = 0; i < 8; ++i) h[i] = (half_t)(v[i] * inv);
    *(half8*)(S + base + t * 8) = h;
}

extern "C" void kernel_launch(void* const* d_in, const int* in_sizes, int n_in,
                              void* d_out, int out_size, void* d_ws, size_t ws_size,
                              hipStream_t stream)
{
    const float* x  = (const float*)d_in[0];
    const float* Wq = (const float*)d_in[1];
    const float* Wk = (const float*)d_in[2];
    const float* Wv = (const float*)d_in[3];
    const float* Wp = (const float*)d_in[4];
    const float* bp = (const float*)d_in[5];
    float* out = (float*)d_out;

    char* ws = (char*)d_ws;
    const long long MB = 1024LL * 1024LL;
    half_t* WqkvT = (half_t*)(ws + 0 * MB);   // [3072][1024] = WqT|WkT|WvT
    half_t* WpT   = (half_t*)(ws + 6 * MB);
    half_t* q     = (half_t*)(ws + 8 * MB);   // [8][2048][1024]; later ctx
    half_t* k     = (half_t*)(ws + 40 * MB);
    half_t* vT    = (half_t*)(ws + 72 * MB);  // [8][1024][2048]
    half_t* x16   = (half_t*)(ws + 104 * MB); // dead after QKV
    half_t* S     = (half_t*)(ws + 104 * MB); // [8][2048][2048] fp16, overlays x16

    dim3 blk(128);
    cast16<<<8192, dim3(256), 0, stream>>>(x, x16);
    cast_transpose4<<<dim3(32, 32, 4), dim3(32, 8), 0, stream>>>(Wq, Wk, Wv, Wp, WqkvT);

    // fused QKV: [16384,1024] @ [3072,1024]^T, routed epilogue. 3072 blocks.
    gemm16<2><<<dim3(24, 128, 1), blk, 0, stream>>>(
        x16, WqkvT, q, k, vT, nullptr, 1024, 1024, 1024, 0, 0, 0, 0);

    // S = q @ k^T (fp16 out), all 8 batches. 2048 blocks.
    gemm16<0><<<dim3(16, 16, 8), blk, 0, stream>>>(
        q, k, S, nullptr, nullptr, nullptr, 1024, 1024, 1024, 2048,
        2048LL * 1024, 2048LL * 1024, 2048LL * 2048);

    // P = softmax(S) in place
    softmax_rows<<<8 * 2048, dim3(256), 0, stream>>>(S);

    // ctx = P @ vT^T (fp16), overwrites q. 1024 blocks.
    gemm16<0><<<dim3(8, 16, 8), blk, 0, stream>>>(
        S, vT, q, nullptr, nullptr, nullptr, 2048, 2048, 2048, 1024,
        2048LL * 2048, 1024LL * 2048, 2048LL * 1024);

    // out = ctx @ WpT^T + bp (fp32). 1024 blocks.
    gemm16<1><<<dim3(8, 128, 1), blk, 0, stream>>>(
        q, WpT, out, nullptr, nullptr, bp, 1024, 1024, 1024, 1024, 0, 0, 0);
}

// Round 6
// 543.894 us; speedup vs baseline: 1.0623x; 1.0623x over previous
//
#include <hip/hip_runtime.h>

// MiniSelfAttention: B=8, T=2048, D=1024, fp32 in/out, fp16 MFMA internally.
// R6: macro-tile enlargement — 256x128 block tile, 512 threads = 8 waves of
// the proven 64x64 wave geometry (4x4 16x16x32 frags, 56 VGPR/wave shape).
// Halves L2 staging bytes/FLOP (24 KB per 2.1 MFLOP block-iter) and
// barriers/FLOP vs R2-R5's 128x128. Dbuf + raw-barrier pipeline from R4.
//
// ws layout (MB):
//   [0,6)    WqkvT = WqT|WkT|WvT contiguous (fp16 [3072][1024])
//   [6,8)    WpT fp16
//   [8,40)   q fp16 [8][2048][1024]   (later overwritten by ctx)
//   [40,72)  k fp16
//   [72,104) vT fp16 [8][1024][2048]
//   [104,136) x16 fp16 (dead after QKV), overlaid by:
//   [104,168) S fp16 [8][2048][2048]  (softmaxed in place -> P)

typedef _Float16 half_t;
typedef _Float16 half8 __attribute__((ext_vector_type(8)));
typedef float floatx4 __attribute__((ext_vector_type(4)));

// async global->LDS, 16B per lane; LDS dest = wave-uniform base + lane*16
#define GLD16(gp, lp)                                                          \
    __builtin_amdgcn_global_load_lds(                                          \
        (const __attribute__((address_space(1))) void*)(gp),                   \
        (__attribute__((address_space(3))) void*)(lp), 16, 0, 0)

#define WAIT_VM0()  asm volatile("s_waitcnt vmcnt(0)" ::: "memory")
#define BARRIER()   do { asm volatile("" ::: "memory");                        \
                         __builtin_amdgcn_s_barrier();                         \
                         asm volatile("" ::: "memory"); } while (0)

// ---------------------------------------------------------------------------
// fp16 NT GEMM: 256x128 tile, BK=32, 8 waves (64x64 each, 4x4 frags),
// double-buffered LDS + raw-barrier pipeline (1 barrier/iter)
// EPI: 0 = fp16 C store; 1 = fp32 C + bias; 2 = QKV-routed (q*1/32, k, vT)
// ---------------------------------------------------------------------------
template<int EPI>
__global__ __launch_bounds__(512, 4)
void gemm16(const half_t* __restrict__ A, const half_t* __restrict__ B,
            void* __restrict__ Cv, void* __restrict__ C2, void* __restrict__ C3,
            const float* __restrict__ bias, int K, int lda, int ldb, int ldc,
            long long bsA, long long bsB, long long bsC)
{
    __shared__ half_t As[2 * 256 * 32];  // 32 KB, unpadded (global_load_lds)
    __shared__ half_t Bs[2 * 128 * 32];  // 16 KB

    const int tid  = threadIdx.x;
    const int lane = tid & 63;
    const int wid  = tid >> 6;           // 0..7
    const int wr   = (wid >> 1) * 64;    // wave grid 4 (rows) x 2 (cols)
    const int wc   = (wid & 1) * 64;
    const long long z = blockIdx.z;
    const int rowBase = blockIdx.y * 256;
    const int colBase = blockIdx.x * 128;

    // staging: 384 rows of 64B (256 A + 128 B) = 24 groups of 16 rows,
    // 3 groups per wave, one GLD16 (16 rows x 64B = 1KB) per group.
    const int lrow = lane >> 2;          // 0..15
    const int scol = (lane & 3) * 8;     // halves offset within 64B row

    const half_t* gptr[3];
    int  lofs[3];
    bool isA[3];
    #pragma unroll
    for (int j = 0; j < 3; ++j) {
        const int r16 = (wid * 3 + j) * 16;
        if (r16 < 256) {
            gptr[j] = A + z * bsA + (long long)(rowBase + r16 + lrow) * lda + scol;
            lofs[j] = r16 * 32;
            isA[j]  = true;
        } else {
            gptr[j] = B + z * bsB + (long long)(colBase + (r16 - 256) + lrow) * ldb + scol;
            lofs[j] = (r16 - 256) * 32;
            isA[j]  = false;
        }
    }

    floatx4 acc[4][4];
    #pragma unroll
    for (int m = 0; m < 4; ++m)
        #pragma unroll
        for (int n = 0; n < 4; ++n)
            #pragma unroll
            for (int j = 0; j < 4; ++j) acc[m][n][j] = 0.0f;

    const int fr = lane & 15;
    const int fk = (lane >> 4) * 8;
    const int nIter = K >> 5;

    // prolog: stage tile 0 into buffer 0
    #pragma unroll
    for (int j = 0; j < 3; ++j)
        GLD16(gptr[j], isA[j] ? &As[lofs[j]] : &Bs[lofs[j]]);
    WAIT_VM0();
    BARRIER();

    for (int it = 0; it < nIter; ++it) {
        const int ca = (it & 1) * 8192;      // current A buffer offset (halves)
        const int cb = (it & 1) * 4096;      // current B buffer offset
        const int na = 8192 - ca;
        const int nb = 4096 - cb;
        // prefetch tile it+1 into the other buffer (DMA flies during MFMA)
        if (it + 1 < nIter) {
            const int kk = (it + 1) << 5;
            #pragma unroll
            for (int j = 0; j < 3; ++j)
                GLD16(gptr[j] + kk, isA[j] ? &As[na + lofs[j]] : &Bs[nb + lofs[j]]);
        }

        half8 af[4], bf[4];
        #pragma unroll
        for (int m = 0; m < 4; ++m)
            af[m] = *(const half8*)&As[ca + (wr + m * 16 + fr) * 32 + fk];
        #pragma unroll
        for (int n = 0; n < 4; ++n)
            bf[n] = *(const half8*)&Bs[cb + (wc + n * 16 + fr) * 32 + fk];
        #pragma unroll
        for (int m = 0; m < 4; ++m)
            #pragma unroll
            for (int n = 0; n < 4; ++n)
                acc[m][n] = __builtin_amdgcn_mfma_f32_16x16x32_f16(af[m], bf[n], acc[m][n], 0, 0, 0);

        // drain own prefetch DMAs (hidden behind the MFMA above), then publish
        WAIT_VM0();
        BARRIER();
    }

    // epilogue: C/D layout col=lane&15, row=(lane>>4)*4+reg (gfx950-verified)
    const int ecol = lane & 15;
    const int q4   = (lane >> 4) * 4;
    #pragma unroll
    for (int m = 0; m < 4; ++m) {
        #pragma unroll
        for (int n = 0; n < 4; ++n) {
            const int gcol = colBase + wc + n * 16 + ecol;
            #pragma unroll
            for (int r = 0; r < 4; ++r) {
                const int grow = rowBase + wr + m * 16 + q4 + r;
                float v = acc[m][n][r];
                if (EPI == 0) {
                    ((half_t*)Cv)[z * bsC + (long long)grow * ldc + gcol] = (half_t)v;
                } else if (EPI == 1) {
                    ((float*)Cv)[(long long)grow * ldc + gcol] = v + bias[gcol];
                } else {
                    // QKV routing: block-uniform on colBase (128-col block
                    // lies entirely inside one of q/k/v's 1024-col spans)
                    const int mat = colBase >> 10;      // 0=q, 1=k, 2=v
                    const int c   = gcol & 1023;
                    if (mat == 0) {
                        ((half_t*)Cv)[(long long)grow * 1024 + c] = (half_t)(v * 0.03125f);
                    } else if (mat == 1) {
                        ((half_t*)C2)[(long long)grow * 1024 + c] = (half_t)v;
                    } else {
                        // vT[b][c][t], b=grow>>11, t=grow&2047
                        const long long bb = grow >> 11;
                        const long long tt = grow & 2047;
                        ((half_t*)C3)[bb * (1024LL * 2048) + (long long)c * 2048 + tt] = (half_t)v;
                    }
                }
            }
        }
    }
}

// fp32 -> fp16 flat cast, 8 elems/thread
__global__ __launch_bounds__(256)
void cast16(const float* __restrict__ x, half_t* __restrict__ y)
{
    const long long i = ((long long)blockIdx.x * 256 + threadIdx.x) * 8;
    floatx4 a = *(const floatx4*)(x + i);
    floatx4 b = *(const floatx4*)(x + i + 4);
    half8 h;
    #pragma unroll
    for (int j = 0; j < 4; ++j) { h[j] = (half_t)a[j]; h[j + 4] = (half_t)b[j]; }
    *(half8*)(y + i) = h;
}

// 1024x1024 fp32 -> fp16 transposed; grid.z selects which weight
__global__ __launch_bounds__(256)
void cast_transpose4(const float* __restrict__ W0, const float* __restrict__ W1,
                     const float* __restrict__ W2, const float* __restrict__ W3,
                     half_t* __restrict__ WT)
{
    const float* W = (blockIdx.z == 0) ? W0 : (blockIdx.z == 1) ? W1
                   : (blockIdx.z == 2) ? W2 : W3;
    half_t* O = WT + (long long)blockIdx.z * 1024 * 1024;
    __shared__ float t[32][33];
    const int bx = blockIdx.x * 32, by = blockIdx.y * 32;
    const int tx = threadIdx.x, ty = threadIdx.y;
    #pragma unroll
    for (int i = 0; i < 32; i += 8)
        t[ty + i][tx] = W[(long long)(by + ty + i) * 1024 + bx + tx];
    __syncthreads();
    #pragma unroll
    for (int i = 0; i < 32; i += 8)
        O[(long long)(bx + ty + i) * 1024 + by + tx] = (half_t)t[tx][ty + i];
}

// in-place fp16 row softmax over 2048; one 256-thr block per row; half8 I/O
__global__ __launch_bounds__(256)
void softmax_rows(half_t* __restrict__ S)
{
    const long long base = (long long)blockIdx.x * 2048;
    const int t = threadIdx.x;
    half8 h = *(const half8*)(S + base + t * 8);
    float v[8];
    #pragma unroll
    for (int i = 0; i < 8; ++i) v[i] = (float)h[i];
    float m = -3.0e38f;
    #pragma unroll
    for (int i = 0; i < 8; ++i) m = fmaxf(m, v[i]);
    #pragma unroll
    for (int off = 32; off > 0; off >>= 1) m = fmaxf(m, __shfl_down(m, off));
    __shared__ float redm[4], reds[4];
    const int lane = t & 63, wid = t >> 6;
    if (lane == 0) redm[wid] = m;
    __syncthreads();
    const float M = fmaxf(fmaxf(redm[0], redm[1]), fmaxf(redm[2], redm[3]));
    float s = 0.f;
    #pragma unroll
    for (int i = 0; i < 8; ++i) { v[i] = __expf(v[i] - M); s += v[i]; }
    #pragma unroll
    for (int off = 32; off > 0; off >>= 1) s += __shfl_down(s, off);
    if (lane == 0) reds[wid] = s;
    __syncthreads();
    const float inv = 1.0f / (reds[0] + reds[1] + reds[2] + reds[3]);
    #pragma unroll
    for (int i = 0; i < 8; ++i) h[i] = (half_t)(v[i] * inv);
    *(half8*)(S + base + t * 8) = h;
}

extern "C" void kernel_launch(void* const* d_in, const int* in_sizes, int n_in,
                              void* d_out, int out_size, void* d_ws, size_t ws_size,
                              hipStream_t stream)
{
    const float* x  = (const float*)d_in[0];
    const float* Wq = (const float*)d_in[1];
    const float* Wk = (const float*)d_in[2];
    const float* Wv = (const float*)d_in[3];
    const float* Wp = (const float*)d_in[4];
    const float* bp = (const float*)d_in[5];
    float* out = (float*)d_out;

    char* ws = (char*)d_ws;
    const long long MB = 1024LL * 1024LL;
    half_t* WqkvT = (half_t*)(ws + 0 * MB);   // [3072][1024] = WqT|WkT|WvT
    half_t* WpT   = (half_t*)(ws + 6 * MB);
    half_t* q     = (half_t*)(ws + 8 * MB);   // [8][2048][1024]; later ctx
    half_t* k     = (half_t*)(ws + 40 * MB);
    half_t* vT    = (half_t*)(ws + 72 * MB);  // [8][1024][2048]
    half_t* x16   = (half_t*)(ws + 104 * MB); // dead after QKV
    half_t* S     = (half_t*)(ws + 104 * MB); // [8][2048][2048] fp16, overlays x16

    dim3 blk(512);
    cast16<<<8192, dim3(256), 0, stream>>>(x, x16);
    cast_transpose4<<<dim3(32, 32, 4), dim3(32, 8), 0, stream>>>(Wq, Wk, Wv, Wp, WqkvT);

    // fused QKV: [16384,1024] @ [3072,1024]^T, routed epilogue. 1536 blocks.
    gemm16<2><<<dim3(24, 64, 1), blk, 0, stream>>>(
        x16, WqkvT, q, k, vT, nullptr, 1024, 1024, 1024, 0, 0, 0, 0);

    // S = q @ k^T (fp16 out), all 8 batches. 1024 blocks.
    gemm16<0><<<dim3(16, 8, 8), blk, 0, stream>>>(
        q, k, S, nullptr, nullptr, nullptr, 1024, 1024, 1024, 2048,
        2048LL * 1024, 2048LL * 1024, 2048LL * 2048);

    // P = softmax(S) in place
    softmax_rows<<<8 * 2048, dim3(256), 0, stream>>>(S);

    // ctx = P @ vT^T (fp16), overwrites q. 512 blocks.
    gemm16<0><<<dim3(8, 8, 8), blk, 0, stream>>>(
        S, vT, q, nullptr, nullptr, nullptr, 2048, 2048, 2048, 1024,
        2048LL * 2048, 1024LL * 2048, 2048LL * 1024);

    // out = ctx @ WpT^T + bp (fp32). 512 blocks.
    gemm16<1><<<dim3(8, 64, 1), blk, 0, stream>>>(
        q, WpT, out, nullptr, nullptr, bp, 1024, 1024, 1024, 1024, 0, 0, 0);
}

// Round 7
// 541.005 us; speedup vs baseline: 1.0680x; 1.0053x over previous
//
#include <hip/hip_runtime.h>

// MiniSelfAttention: B=8, T=2048, D=1024, fp32 in/out, fp16 MFMA internally.
// R7: XOR-swizzled LDS — kills the 8-way bank conflict in fragment reads.
// Store side: lane stages global 16B-chunk ((lane&3)^((lane>>3)&3)) of its row
// (global_load_lds dest is fixed base+lane*16, so we permute the SOURCE).
// LDS slot (row r, chunk sc) thus holds global chunk sc^((r>>1)&3).
// Read side: frag chunk = q ^ ((fr>>1)&3) -> 16 fr values spread across all
// 8 bank-quads per q -> 2-way max (free, m136). Geometry = R6 (256x128 tile,
// 8 waves of 64x64, dbuf + raw-barrier pipeline).
//
// ws layout (MB):
//   [0,6)    WqkvT = WqT|WkT|WvT contiguous (fp16 [3072][1024])
//   [6,8)    WpT fp16
//   [8,40)   q fp16 [8][2048][1024]   (later overwritten by ctx)
//   [40,72)  k fp16
//   [72,104) vT fp16 [8][1024][2048]
//   [104,136) x16 fp16 (dead after QKV), overlaid by:
//   [104,168) S fp16 [8][2048][2048]  (softmaxed in place -> P)

typedef _Float16 half_t;
typedef _Float16 half8 __attribute__((ext_vector_type(8)));
typedef float floatx4 __attribute__((ext_vector_type(4)));

// async global->LDS, 16B per lane; LDS dest = wave-uniform base + lane*16
#define GLD16(gp, lp)                                                          \
    __builtin_amdgcn_global_load_lds(                                          \
        (const __attribute__((address_space(1))) void*)(gp),                   \
        (__attribute__((address_space(3))) void*)(lp), 16, 0, 0)

#define WAIT_VM0()  asm volatile("s_waitcnt vmcnt(0)" ::: "memory")
#define BARRIER()   do { asm volatile("" ::: "memory");                        \
                         __builtin_amdgcn_s_barrier();                         \
                         asm volatile("" ::: "memory"); } while (0)

// ---------------------------------------------------------------------------
// fp16 NT GEMM: 256x128 tile, BK=32, 8 waves (64x64 each, 4x4 frags),
// double-buffered LDS + raw-barrier pipeline, XOR-swizzled LDS chunks.
// EPI: 0 = fp16 C store; 1 = fp32 C + bias; 2 = QKV-routed (q*1/32, k, vT)
// ---------------------------------------------------------------------------
template<int EPI>
__global__ __launch_bounds__(512, 4)
void gemm16(const half_t* __restrict__ A, const half_t* __restrict__ B,
            void* __restrict__ Cv, void* __restrict__ C2, void* __restrict__ C3,
            const float* __restrict__ bias, int K, int lda, int ldb, int ldc,
            long long bsA, long long bsB, long long bsC)
{
    __shared__ half_t As[2 * 256 * 32];  // 32 KB, unpadded (global_load_lds)
    __shared__ half_t Bs[2 * 128 * 32];  // 16 KB

    const int tid  = threadIdx.x;
    const int lane = tid & 63;
    const int wid  = tid >> 6;           // 0..7
    const int wr   = (wid >> 1) * 64;    // wave grid 4 (rows) x 2 (cols)
    const int wc   = (wid & 1) * 64;
    const long long z = blockIdx.z;
    const int rowBase = blockIdx.y * 256;
    const int colBase = blockIdx.x * 128;

    // staging: 384 rows of 64B (256 A + 128 B) = 24 groups of 16 rows,
    // 3 groups per wave, one GLD16 (16 rows x 64B = 1KB) per group.
    // SWIZZLE: lane stages global chunk (lane&3)^((lane>>3)&3) of its row,
    // so LDS slot (r, sc) holds global chunk sc^((r>>1)&3).
    const int lrow = lane >> 2;                              // 0..15
    const int scol = (((lane & 3) ^ ((lane >> 3) & 3))) * 8; // swizzled chunk

    const half_t* gptr[3];
    int  lofs[3];
    bool isA[3];
    #pragma unroll
    for (int j = 0; j < 3; ++j) {
        const int r16 = (wid * 3 + j) * 16;
        if (r16 < 256) {
            gptr[j] = A + z * bsA + (long long)(rowBase + r16 + lrow) * lda + scol;
            lofs[j] = r16 * 32;
            isA[j]  = true;
        } else {
            gptr[j] = B + z * bsB + (long long)(colBase + (r16 - 256) + lrow) * ldb + scol;
            lofs[j] = (r16 - 256) * 32;
            isA[j]  = false;
        }
    }

    floatx4 acc[4][4];
    #pragma unroll
    for (int m = 0; m < 4; ++m)
        #pragma unroll
        for (int n = 0; n < 4; ++n)
            #pragma unroll
            for (int j = 0; j < 4; ++j) acc[m][n][j] = 0.0f;

    const int fr  = lane & 15;
    // read-side swizzle: global chunk q lives at LDS chunk q ^ ((fr>>1)&3)
    const int fks = (((lane >> 4) ^ ((lane >> 1) & 3))) * 8;
    const int nIter = K >> 5;

    // prolog: stage tile 0 into buffer 0
    #pragma unroll
    for (int j = 0; j < 3; ++j)
        GLD16(gptr[j], isA[j] ? &As[lofs[j]] : &Bs[lofs[j]]);
    WAIT_VM0();
    BARRIER();

    for (int it = 0; it < nIter; ++it) {
        const int ca = (it & 1) * 8192;      // current A buffer offset (halves)
        const int cb = (it & 1) * 4096;      // current B buffer offset
        const int na = 8192 - ca;
        const int nb = 4096 - cb;
        // prefetch tile it+1 into the other buffer (DMA flies during MFMA)
        if (it + 1 < nIter) {
            const int kk = (it + 1) << 5;
            #pragma unroll
            for (int j = 0; j < 3; ++j)
                GLD16(gptr[j] + kk, isA[j] ? &As[na + lofs[j]] : &Bs[nb + lofs[j]]);
        }

        half8 af[4], bf[4];
        #pragma unroll
        for (int m = 0; m < 4; ++m)
            af[m] = *(const half8*)&As[ca + (wr + m * 16 + fr) * 32 + fks];
        #pragma unroll
        for (int n = 0; n < 4; ++n)
            bf[n] = *(const half8*)&Bs[cb + (wc + n * 16 + fr) * 32 + fks];
        #pragma unroll
        for (int m = 0; m < 4; ++m)
            #pragma unroll
            for (int n = 0; n < 4; ++n)
                acc[m][n] = __builtin_amdgcn_mfma_f32_16x16x32_f16(af[m], bf[n], acc[m][n], 0, 0, 0);

        // drain own prefetch DMAs (hidden behind the MFMA above), then publish
        WAIT_VM0();
        BARRIER();
    }

    // epilogue: C/D layout col=lane&15, row=(lane>>4)*4+reg (gfx950-verified)
    const int ecol = lane & 15;
    const int q4   = (lane >> 4) * 4;
    #pragma unroll
    for (int m = 0; m < 4; ++m) {
        #pragma unroll
        for (int n = 0; n < 4; ++n) {
            const int gcol = colBase + wc + n * 16 + ecol;
            #pragma unroll
            for (int r = 0; r < 4; ++r) {
                const int grow = rowBase + wr + m * 16 + q4 + r;
                float v = acc[m][n][r];
                if (EPI == 0) {
                    ((half_t*)Cv)[z * bsC + (long long)grow * ldc + gcol] = (half_t)v;
                } else if (EPI == 1) {
                    ((float*)Cv)[(long long)grow * ldc + gcol] = v + bias[gcol];
                } else {
                    // QKV routing: block-uniform on colBase (128-col block
                    // lies entirely inside one of q/k/v's 1024-col spans)
                    const int mat = colBase >> 10;      // 0=q, 1=k, 2=v
                    const int c   = gcol & 1023;
                    if (mat == 0) {
                        ((half_t*)Cv)[(long long)grow * 1024 + c] = (half_t)(v * 0.03125f);
                    } else if (mat == 1) {
                        ((half_t*)C2)[(long long)grow * 1024 + c] = (half_t)v;
                    } else {
                        // vT[b][c][t], b=grow>>11, t=grow&2047
                        const long long bb = grow >> 11;
                        const long long tt = grow & 2047;
                        ((half_t*)C3)[bb * (1024LL * 2048) + (long long)c * 2048 + tt] = (half_t)v;
                    }
                }
            }
        }
    }
}

// fp32 -> fp16 flat cast, 8 elems/thread
__global__ __launch_bounds__(256)
void cast16(const float* __restrict__ x, half_t* __restrict__ y)
{
    const long long i = ((long long)blockIdx.x * 256 + threadIdx.x) * 8;
    floatx4 a = *(const floatx4*)(x + i);
    floatx4 b = *(const floatx4*)(x + i + 4);
    half8 h;
    #pragma unroll
    for (int j = 0; j < 4; ++j) { h[j] = (half_t)a[j]; h[j + 4] = (half_t)b[j]; }
    *(half8*)(y + i) = h;
}

// 1024x1024 fp32 -> fp16 transposed; grid.z selects which weight
__global__ __launch_bounds__(256)
void cast_transpose4(const float* __restrict__ W0, const float* __restrict__ W1,
                     const float* __restrict__ W2, const float* __restrict__ W3,
                     half_t* __restrict__ WT)
{
    const float* W = (blockIdx.z == 0) ? W0 : (blockIdx.z == 1) ? W1
                   : (blockIdx.z == 2) ? W2 : W3;
    half_t* O = WT + (long long)blockIdx.z * 1024 * 1024;
    __shared__ float t[32][33];
    const int bx = blockIdx.x * 32, by = blockIdx.y * 32;
    const int tx = threadIdx.x, ty = threadIdx.y;
    #pragma unroll
    for (int i = 0; i < 32; i += 8)
        t[ty + i][tx] = W[(long long)(by + ty + i) * 1024 + bx + tx];
    __syncthreads();
    #pragma unroll
    for (int i = 0; i < 32; i += 8)
        O[(long long)(bx + ty + i) * 1024 + by + tx] = (half_t)t[tx][ty + i];
}

// in-place fp16 row softmax over 2048; one 256-thr block per row; half8 I/O
__global__ __launch_bounds__(256)
void softmax_rows(half_t* __restrict__ S)
{
    const long long base = (long long)blockIdx.x * 2048;
    const int t = threadIdx.x;
    half8 h = *(const half8*)(S + base + t * 8);
    float v[8];
    #pragma unroll
    for (int i = 0; i < 8; ++i) v[i] = (float)h[i];
    float m = -3.0e38f;
    #pragma unroll
    for (int i = 0; i < 8; ++i) m = fmaxf(m, v[i]);
    #pragma unroll
    for (int off = 32; off > 0; off >>= 1) m = fmaxf(m, __shfl_down(m, off));
    __shared__ float redm[4], reds[4];
    const int lane = t & 63, wid = t >> 6;
    if (lane == 0) redm[wid] = m;
    __syncthreads();
    const float M = fmaxf(fmaxf(redm[0], redm[1]), fmaxf(redm[2], redm[3]));
    float s = 0.f;
    #pragma unroll
    for (int i = 0; i < 8; ++i) { v[i] = __expf(v[i] - M); s += v[i]; }
    #pragma unroll
    for (int off = 32; off > 0; off >>= 1) s += __shfl_down(s, off);
    if (lane == 0) reds[wid] = s;
    __syncthreads();
    const float inv = 1.0f / (reds[0] + reds[1] + reds[2] + reds[3]);
    #pragma unroll
    for (int i = 0; i < 8; ++i) h[i] = (half_t)(v[i] * inv);
    *(half8*)(S + base + t * 8) = h;
}

extern "C" void kernel_launch(void* const* d_in, const int* in_sizes, int n_in,
                              void* d_out, int out_size, void* d_ws, size_t ws_size,
                              hipStream_t stream)
{
    const float* x  = (const float*)d_in[0];
    const float* Wq = (const float*)d_in[1];
    const float* Wk = (const float*)d_in[2];
    const float* Wv = (const float*)d_in[3];
    const float* Wp = (const float*)d_in[4];
    const float* bp = (const float*)d_in[5];
    float* out = (float*)d_out;

    char* ws = (char*)d_ws;
    const long long MB = 1024LL * 1024LL;
    half_t* WqkvT = (half_t*)(ws + 0 * MB);   // [3072][1024] = WqT|WkT|WvT
    half_t* WpT   = (half_t*)(ws + 6 * MB);
    half_t* q     = (half_t*)(ws + 8 * MB);   // [8][2048][1024]; later ctx
    half_t* k     = (half_t*)(ws + 40 * MB);
    half_t* vT    = (half_t*)(ws + 72 * MB);  // [8][1024][2048]
    half_t* x16   = (half_t*)(ws + 104 * MB); // dead after QKV
    half_t* S     = (half_t*)(ws + 104 * MB); // [8][2048][2048] fp16, overlays x16

    dim3 blk(512);
    cast16<<<8192, dim3(256), 0, stream>>>(x, x16);
    cast_transpose4<<<dim3(32, 32, 4), dim3(32, 8), 0, stream>>>(Wq, Wk, Wv, Wp, WqkvT);

    // fused QKV: [16384,1024] @ [3072,1024]^T, routed epilogue. 1536 blocks.
    gemm16<2><<<dim3(24, 64, 1), blk, 0, stream>>>(
        x16, WqkvT, q, k, vT, nullptr, 1024, 1024, 1024, 0, 0, 0, 0);

    // S = q @ k^T (fp16 out), all 8 batches. 1024 blocks.
    gemm16<0><<<dim3(16, 8, 8), blk, 0, stream>>>(
        q, k, S, nullptr, nullptr, nullptr, 1024, 1024, 1024, 2048,
        2048LL * 1024, 2048LL * 1024, 2048LL * 2048);

    // P = softmax(S) in place
    softmax_rows<<<8 * 2048, dim3(256), 0, stream>>>(S);

    // ctx = P @ vT^T (fp16), overwrites q. 512 blocks.
    gemm16<0><<<dim3(8, 8, 8), blk, 0, stream>>>(
        S, vT, q, nullptr, nullptr, nullptr, 2048, 2048, 2048, 1024,
        2048LL * 2048, 1024LL * 2048, 2048LL * 1024);

    // out = ctx @ WpT^T + bp (fp32). 512 blocks.
    gemm16<1><<<dim3(8, 64, 1), blk, 0, stream>>>(
        q, WpT, out, nullptr, nullptr, bp, 1024, 1024, 1024, 1024, 0, 0, 0);
}